// Round 1
// baseline (1177.165 us; speedup 1.0000x reference)
//
#include <hip/hip_runtime.h>
#include <hip/hip_fp16.h>
#include <math.h>

#define N_TOK   8192
#define D_DIM   1024
#define H_DIM   2048
#define N_EXP   8
#define CAPL    8192   // per-expert list capacity; cnt can never exceed N_TOK

typedef _Float16 f16x8 __attribute__((ext_vector_type(8)));
typedef _Float16 f16x4 __attribute__((ext_vector_type(4)));
typedef float    f32x4 __attribute__((ext_vector_type(4)));

__device__ __forceinline__ void gload16(const void* g, void* l) {
  __builtin_amdgcn_global_load_lds(
      (const __attribute__((address_space(1))) void*)g,
      (__attribute__((address_space(3))) void*)l, 16, 0, 0);
}

// ---------------- fp32 -> fp16 convert (vectorized) ----------------
__global__ __launch_bounds__(256) void cvt_f32_f16(const float* __restrict__ s,
                                                   _Float16* __restrict__ d, int n4) {
  int i = blockIdx.x * 256 + threadIdx.x;
  if (i >= n4) return;
  float4 v = ((const float4*)s)[i];
  f16x4 o;
  o.x = (_Float16)v.x; o.y = (_Float16)v.y; o.z = (_Float16)v.z; o.w = (_Float16)v.w;
  ((f16x4*)d)[i] = o;
}

// ---------------- gating + routing ----------------
// one wave per token; fp64 accumulation so top-2 selection matches numpy ref
__global__ __launch_bounds__(256) void gate_route(
    const float* __restrict__ x, const float* __restrict__ gw,
    const float* __restrict__ gb, int* __restrict__ cnt,
    int* __restrict__ tokL, float* __restrict__ coefL) {
  __shared__ float sgw[N_EXP * D_DIM];  // 32 KB
  for (int i = threadIdx.x; i < N_EXP * D_DIM; i += 256) sgw[i] = gw[i];
  __syncthreads();
  const int w = threadIdx.x >> 6, lane = threadIdx.x & 63;
  const int n = blockIdx.x * 4 + w;
  const float* xp = x + (long)n * D_DIM;
  double acc[N_EXP];
  #pragma unroll
  for (int e = 0; e < N_EXP; e++) acc[e] = 0.0;
  for (int i = 0; i < D_DIM / 64; i++) {
    int d = lane + i * 64;
    double xv = (double)xp[d];
    #pragma unroll
    for (int e = 0; e < N_EXP; e++) acc[e] += xv * (double)sgw[e * D_DIM + d];
  }
  #pragma unroll
  for (int e = 0; e < N_EXP; e++)
    for (int off = 32; off >= 1; off >>= 1)
      acc[e] += __shfl_down(acc[e], off);
  if (lane == 0) {
    double lg[N_EXP];
    #pragma unroll
    for (int e = 0; e < N_EXP; e++) lg[e] = acc[e] + (double)gb[e];
    int i1 = 0;
    for (int e = 1; e < N_EXP; e++) if (lg[e] > lg[i1]) i1 = e;
    int i2 = (i1 == 0) ? 1 : 0;
    for (int e = 0; e < N_EXP; e++) { if (e == i1) continue; if (lg[e] > lg[i2]) i2 = e; }
    double p1 = 1.0 / (1.0 + exp(lg[i2] - lg[i1]));  // == softmax-top2 renormalized
    double p2 = 1.0 - p1;
    int pos1 = atomicAdd(&cnt[i1], 1);
    tokL[i1 * CAPL + pos1] = n * 2;
    coefL[i1 * CAPL + pos1] = (float)p1;
    int pos2 = atomicAdd(&cnt[i2], 1);
    tokL[i2 * CAPL + pos2] = n * 2 + 1;
    coefL[i2 * CAPL + pos2] = (float)p2;
  }
}

// ---------------- stage 1: h = relu(x@W1^T)^2 * (x@W3^T), per expert ----------------
// 128x128 tile over (routed tokens) x (hidden), K=D, dual B (W1,W3) sharing the x tile
__global__ __launch_bounds__(256) void ffn_stage1(
    const _Float16* __restrict__ xh, const _Float16* __restrict__ w1h,
    const _Float16* __restrict__ w3h, const int* __restrict__ cnt,
    const int* __restrict__ tokL, _Float16* __restrict__ hbuf) {
  const int e  = blockIdx.z;
  const int n0 = blockIdx.y * 128;
  const int m0 = blockIdx.x * 128;
  const int c  = cnt[e];
  if (m0 >= c) return;

  __shared__ _Float16 Xs[128 * 32];
  __shared__ _Float16 W1s[128 * 32];
  __shared__ _Float16 W3s[128 * 32];
  __shared__ int sEnt[128];

  const int t = threadIdx.x;
  if (t < 128) {
    int idx = m0 + t;
    if (idx >= c) idx = c - 1;          // clamp: loads valid data, stores are guarded
    sEnt[t] = tokL[e * CAPL + idx];
  }
  __syncthreads();

  const int srow = t >> 2;              // 0..63
  const int c8   = (t & 3) * 8;         // fp16 col offset within 32-wide K tile
  const long xr0 = (long)(sEnt[srow] >> 1);
  const long xr1 = (long)(sEnt[srow + 64] >> 1);
  const _Float16* xg0 = xh + xr0 * D_DIM + c8;
  const _Float16* xg1 = xh + xr1 * D_DIM + c8;
  const _Float16* w1g0 = w1h + ((long)e * H_DIM + n0 + srow) * D_DIM + c8;
  const _Float16* w1g1 = w1g0 + (long)64 * D_DIM;
  const _Float16* w3g0 = w3h + ((long)e * H_DIM + n0 + srow) * D_DIM + c8;
  const _Float16* w3g1 = w3g0 + (long)64 * D_DIM;
  _Float16* lX0  = Xs  + t * 8;
  _Float16* lX1  = Xs  + 2048 + t * 8;
  _Float16* lW10 = W1s + t * 8;
  _Float16* lW11 = W1s + 2048 + t * 8;
  _Float16* lW30 = W3s + t * 8;
  _Float16* lW31 = W3s + 2048 + t * 8;

  const int w = t >> 6, lane = t & 63;
  const int wm = (w & 1) * 64, wn = (w >> 1) * 64;
  const int q = lane >> 4, lr = lane & 15;

  f32x4 au[4][4], av[4][4];
  const f32x4 zz = {0.f, 0.f, 0.f, 0.f};
  #pragma unroll
  for (int i = 0; i < 4; i++)
    #pragma unroll
    for (int j = 0; j < 4; j++) { au[i][j] = zz; av[i][j] = zz; }

  for (int k0 = 0; k0 < D_DIM; k0 += 32) {
    __syncthreads();
    gload16(xg0 + k0, lX0);
    gload16(xg1 + k0, lX1);
    gload16(w1g0 + k0, lW10);
    gload16(w1g1 + k0, lW11);
    gload16(w3g0 + k0, lW30);
    gload16(w3g1 + k0, lW31);
    __syncthreads();

    f16x8 a[4], b1[4], b3[4];
    #pragma unroll
    for (int i = 0; i < 4; i++) {
      a[i]  = *(const f16x8*)(Xs  + (wm + i * 16 + lr) * 32 + q * 8);
      b1[i] = *(const f16x8*)(W1s + (wn + i * 16 + lr) * 32 + q * 8);
      b3[i] = *(const f16x8*)(W3s + (wn + i * 16 + lr) * 32 + q * 8);
    }
    #pragma unroll
    for (int mi = 0; mi < 4; mi++)
      #pragma unroll
      for (int ni = 0; ni < 4; ni++) {
        au[mi][ni] = __builtin_amdgcn_mfma_f32_16x16x32_f16(a[mi], b1[ni], au[mi][ni], 0, 0, 0);
        av[mi][ni] = __builtin_amdgcn_mfma_f32_16x16x32_f16(a[mi], b3[ni], av[mi][ni], 0, 0, 0);
      }
  }

  // epilogue: h = relu(u)^2 * v  (C/D layout: col = lane&15, row = quad*4 + reg)
  #pragma unroll
  for (int mi = 0; mi < 4; mi++) {
    #pragma unroll
    for (int r = 0; r < 4; r++) {
      int ml = wm + mi * 16 + q * 4 + r;
      if (m0 + ml < c) {
        long hrow = (long)sEnt[ml];
        _Float16* hp = hbuf + hrow * H_DIM + n0 + wn + lr;
        #pragma unroll
        for (int ni = 0; ni < 4; ni++) {
          float u = au[mi][ni][r];
          float rl = u > 0.f ? u : 0.f;
          float hv = rl * rl * av[mi][ni][r];
          hp[ni * 16] = (_Float16)hv;
        }
      }
    }
  }
}

// ---------------- stage 2: out += coef * (h @ W2^T), per expert ----------------
__global__ __launch_bounds__(256) void ffn_stage2(
    const _Float16* __restrict__ hbuf, const _Float16* __restrict__ w2h,
    const int* __restrict__ cnt, const int* __restrict__ tokL,
    const float* __restrict__ coefL, float* __restrict__ out) {
  const int e  = blockIdx.z;
  const int n0 = blockIdx.y * 128;   // over D
  const int m0 = blockIdx.x * 128;
  const int c  = cnt[e];
  if (m0 >= c) return;

  __shared__ _Float16 Hs[128 * 32];
  __shared__ _Float16 W2s[128 * 32];
  __shared__ int sEnt[128];
  __shared__ float sCoef[128];

  const int t = threadIdx.x;
  if (t < 128) {
    int idx = m0 + t;
    if (idx >= c) idx = c - 1;
    sEnt[t]  = tokL[e * CAPL + idx];
    sCoef[t] = coefL[e * CAPL + idx];
  }
  __syncthreads();

  const int srow = t >> 2;
  const int c8   = (t & 3) * 8;
  const long hr0 = (long)sEnt[srow];
  const long hr1 = (long)sEnt[srow + 64];
  const _Float16* hg0 = hbuf + hr0 * H_DIM + c8;
  const _Float16* hg1 = hbuf + hr1 * H_DIM + c8;
  const _Float16* w2g0 = w2h + ((long)e * D_DIM + n0 + srow) * H_DIM + c8;
  const _Float16* w2g1 = w2g0 + (long)64 * H_DIM;
  _Float16* lH0 = Hs  + t * 8;
  _Float16* lH1 = Hs  + 2048 + t * 8;
  _Float16* lW0 = W2s + t * 8;
  _Float16* lW1 = W2s + 2048 + t * 8;

  const int w = t >> 6, lane = t & 63;
  const int wm = (w & 1) * 64, wn = (w >> 1) * 64;
  const int q = lane >> 4, lr = lane & 15;

  f32x4 ac[4][4];
  const f32x4 zz = {0.f, 0.f, 0.f, 0.f};
  #pragma unroll
  for (int i = 0; i < 4; i++)
    #pragma unroll
    for (int j = 0; j < 4; j++) ac[i][j] = zz;

  for (int k0 = 0; k0 < H_DIM; k0 += 32) {
    __syncthreads();
    gload16(hg0 + k0, lH0);
    gload16(hg1 + k0, lH1);
    gload16(w2g0 + k0, lW0);
    gload16(w2g1 + k0, lW1);
    __syncthreads();

    f16x8 a[4], b[4];
    #pragma unroll
    for (int i = 0; i < 4; i++) {
      a[i] = *(const f16x8*)(Hs  + (wm + i * 16 + lr) * 32 + q * 8);
      b[i] = *(const f16x8*)(W2s + (wn + i * 16 + lr) * 32 + q * 8);
    }
    #pragma unroll
    for (int mi = 0; mi < 4; mi++)
      #pragma unroll
      for (int ni = 0; ni < 4; ni++)
        ac[mi][ni] = __builtin_amdgcn_mfma_f32_16x16x32_f16(a[mi], b[ni], ac[mi][ni], 0, 0, 0);
  }

  #pragma unroll
  for (int mi = 0; mi < 4; mi++) {
    #pragma unroll
    for (int r = 0; r < 4; r++) {
      int ml = wm + mi * 16 + q * 4 + r;
      if (m0 + ml < c) {
        int ent = sEnt[ml];
        int token = ent >> 1;
        float cf = sCoef[ml];
        float* op = out + (long)token * D_DIM + n0 + wn + lr;
        #pragma unroll
        for (int ni = 0; ni < 4; ni++)
          atomicAdd(op + ni * 16, cf * ac[mi][ni][r]);
      }
    }
  }
}

extern "C" void kernel_launch(void* const* d_in, const int* in_sizes, int n_in,
                              void* d_out, int out_size, void* d_ws, size_t ws_size,
                              hipStream_t stream) {
  (void)in_sizes; (void)n_in; (void)out_size; (void)ws_size;
  const float* x  = (const float*)d_in[0];
  const float* W1 = (const float*)d_in[1];
  const float* W2 = (const float*)d_in[2];   // dict order: x, W1, W2, W3, gate_w, gate_b
  const float* W3 = (const float*)d_in[3];
  const float* gw = (const float*)d_in[4];
  const float* gb = (const float*)d_in[5];
  float* out = (float*)d_out;

  // workspace layout (fp16 elements), ~185 MB total
  _Float16* xh  = (_Float16*)d_ws;
  _Float16* w1h = xh  + (size_t)N_TOK * D_DIM;
  _Float16* w3h = w1h + (size_t)N_EXP * H_DIM * D_DIM;
  _Float16* w2h = w3h + (size_t)N_EXP * H_DIM * D_DIM;
  _Float16* hb  = w2h + (size_t)N_EXP * H_DIM * D_DIM;
  int*   cnt   = (int*)(hb + (size_t)2 * N_TOK * H_DIM);
  int*   tokL  = cnt + 16;
  float* coefL = (float*)(tokL + N_EXP * CAPL);

  hipMemsetAsync(d_out, 0, (size_t)N_TOK * D_DIM * sizeof(float), stream);
  hipMemsetAsync(cnt, 0, 16 * sizeof(int), stream);

  int xn4 = N_TOK * D_DIM / 4;
  cvt_f32_f16<<<(xn4 + 255) / 256, 256, 0, stream>>>(x, xh, xn4);
  int wn4 = N_EXP * H_DIM * D_DIM / 4;
  cvt_f32_f16<<<(wn4 + 255) / 256, 256, 0, stream>>>(W1, w1h, wn4);
  cvt_f32_f16<<<(wn4 + 255) / 256, 256, 0, stream>>>(W3, w3h, wn4);
  cvt_f32_f16<<<(wn4 + 255) / 256, 256, 0, stream>>>(W2, w2h, wn4);

  gate_route<<<N_TOK / 4, 256, 0, stream>>>(x, gw, gb, cnt, tokL, coefL);

  ffn_stage1<<<dim3(64, H_DIM / 128, N_EXP), 256, 0, stream>>>(xh, w1h, w3h, cnt, tokL, hb);
  ffn_stage2<<<dim3(64, D_DIM / 128, N_EXP), 256, 0, stream>>>(hb, w2h, cnt, tokL, coefL, out);
}

// Round 2
// 1146.180 us; speedup vs baseline: 1.0270x; 1.0270x over previous
//
#include <hip/hip_runtime.h>
#include <hip/hip_fp16.h>
#include <math.h>

#define N_TOK   8192
#define D_DIM   1024
#define H_DIM   2048
#define N_EXP   8
#define CAPL    8192   // per-expert list capacity; cnt can never exceed N_TOK

typedef _Float16 f16x8 __attribute__((ext_vector_type(8)));
typedef _Float16 f16x4 __attribute__((ext_vector_type(4)));
typedef float    f32x4 __attribute__((ext_vector_type(4)));

__device__ __forceinline__ void gload16(const void* g, void* l) {
  __builtin_amdgcn_global_load_lds(
      (const __attribute__((address_space(1))) void*)g,
      (__attribute__((address_space(3))) void*)l, 16, 0, 0);
}

// ---------------- fp32 -> fp16 convert (vectorized) ----------------
__global__ __launch_bounds__(256) void cvt_f32_f16(const float* __restrict__ s,
                                                   _Float16* __restrict__ d, int n4) {
  int i = blockIdx.x * 256 + threadIdx.x;
  if (i >= n4) return;
  float4 v = ((const float4*)s)[i];
  f16x4 o;
  o.x = (_Float16)v.x; o.y = (_Float16)v.y; o.z = (_Float16)v.z; o.w = (_Float16)v.w;
  ((f16x4*)d)[i] = o;
}

// ---------------- gating + routing ----------------
// one wave per token; fp64 accumulation so top-2 selection matches numpy ref
__global__ __launch_bounds__(256) void gate_route(
    const float* __restrict__ x, const float* __restrict__ gw,
    const float* __restrict__ gb, int* __restrict__ cnt,
    int* __restrict__ tokL, float* __restrict__ coefL) {
  __shared__ float sgw[N_EXP * D_DIM];  // 32 KB
  for (int i = threadIdx.x; i < N_EXP * D_DIM; i += 256) sgw[i] = gw[i];
  __syncthreads();
  const int w = threadIdx.x >> 6, lane = threadIdx.x & 63;
  const int n = blockIdx.x * 4 + w;
  const float* xp = x + (long)n * D_DIM;
  double acc[N_EXP];
  #pragma unroll
  for (int e = 0; e < N_EXP; e++) acc[e] = 0.0;
  for (int i = 0; i < D_DIM / 64; i++) {
    int d = lane + i * 64;
    double xv = (double)xp[d];
    #pragma unroll
    for (int e = 0; e < N_EXP; e++) acc[e] += xv * (double)sgw[e * D_DIM + d];
  }
  #pragma unroll
  for (int e = 0; e < N_EXP; e++)
    for (int off = 32; off >= 1; off >>= 1)
      acc[e] += __shfl_down(acc[e], off);
  if (lane == 0) {
    double lg[N_EXP];
    #pragma unroll
    for (int e = 0; e < N_EXP; e++) lg[e] = acc[e] + (double)gb[e];
    int i1 = 0;
    for (int e = 1; e < N_EXP; e++) if (lg[e] > lg[i1]) i1 = e;
    int i2 = (i1 == 0) ? 1 : 0;
    for (int e = 0; e < N_EXP; e++) { if (e == i1) continue; if (lg[e] > lg[i2]) i2 = e; }
    double p1 = 1.0 / (1.0 + exp(lg[i2] - lg[i1]));  // == softmax-top2 renormalized
    double p2 = 1.0 - p1;
    int pos1 = atomicAdd(&cnt[i1], 1);
    tokL[i1 * CAPL + pos1] = n * 2;
    coefL[i1 * CAPL + pos1] = (float)p1;
    int pos2 = atomicAdd(&cnt[i2], 1);
    tokL[i2 * CAPL + pos2] = n * 2 + 1;
    coefL[i2 * CAPL + pos2] = (float)p2;
  }
}

// ---------------- stage 1: h = relu(x@W1^T)^2 * (x@W3^T), per expert ----------------
// 128x128 tile, K=D, dual B (W1,W3), double-buffered LDS: one barrier per K-iter,
// loads for k+1 issue right after the barrier and overlap with iter k's MFMA.
__global__ __launch_bounds__(256, 3) void ffn_stage1(
    const _Float16* __restrict__ xh, const _Float16* __restrict__ w1h,
    const _Float16* __restrict__ w3h, const int* __restrict__ cnt,
    const int* __restrict__ tokL, _Float16* __restrict__ hbuf) {
  const int e  = blockIdx.z;
  const int n0 = blockIdx.y * 128;
  const int m0 = blockIdx.x * 128;
  const int c  = cnt[e];
  if (m0 >= c) return;

  __shared__ _Float16 Xs[2][128 * 32];   // 16 KB
  __shared__ _Float16 W1s[2][128 * 32];  // 16 KB
  __shared__ _Float16 W3s[2][128 * 32];  // 16 KB
  __shared__ int sEnt[128];

  const int t = threadIdx.x;
  if (t < 128) {
    int idx = m0 + t;
    if (idx >= c) idx = c - 1;          // clamp: loads valid data, stores are guarded
    sEnt[t] = tokL[e * CAPL + idx];
  }
  __syncthreads();

  const int srow = t >> 2;              // 0..63
  const int c8   = (t & 3) * 8;         // fp16 col offset within 32-wide K tile
  const long xr0 = (long)(sEnt[srow] >> 1);
  const long xr1 = (long)(sEnt[srow + 64] >> 1);
  const _Float16* xg0 = xh + xr0 * D_DIM + c8;
  const _Float16* xg1 = xh + xr1 * D_DIM + c8;
  const _Float16* w1g0 = w1h + ((long)e * H_DIM + n0 + srow) * D_DIM + c8;
  const _Float16* w1g1 = w1g0 + (long)64 * D_DIM;
  const _Float16* w3g0 = w3h + ((long)e * H_DIM + n0 + srow) * D_DIM + c8;
  const _Float16* w3g1 = w3g0 + (long)64 * D_DIM;
  const int l8 = t * 8;

  const int w = t >> 6, lane = t & 63;
  const int wm = (w & 1) * 64, wn = (w >> 1) * 64;
  const int q = lane >> 4, lr = lane & 15;

  f32x4 au[4][4], av[4][4];
  const f32x4 zz = {0.f, 0.f, 0.f, 0.f};
  #pragma unroll
  for (int i = 0; i < 4; i++)
    #pragma unroll
    for (int j = 0; j < 4; j++) { au[i][j] = zz; av[i][j] = zz; }

  // prefetch k0 = 0 into buffer 0
  gload16(xg0,  &Xs[0][l8]);
  gload16(xg1,  &Xs[0][2048 + l8]);
  gload16(w1g0, &W1s[0][l8]);
  gload16(w1g1, &W1s[0][2048 + l8]);
  gload16(w3g0, &W3s[0][l8]);
  gload16(w3g1, &W3s[0][2048 + l8]);

  int p = 0;
  for (int k0 = 0; k0 < D_DIM; k0 += 32) {
    __syncthreads();                     // drains vmcnt(0): buffer p is ready
    int kn = k0 + 32;
    if (kn < D_DIM) {                    // issue next tile into buffer p^1
      int pn = p ^ 1;
      gload16(xg0 + kn,  &Xs[pn][l8]);
      gload16(xg1 + kn,  &Xs[pn][2048 + l8]);
      gload16(w1g0 + kn, &W1s[pn][l8]);
      gload16(w1g1 + kn, &W1s[pn][2048 + l8]);
      gload16(w3g0 + kn, &W3s[pn][l8]);
      gload16(w3g1 + kn, &W3s[pn][2048 + l8]);
    }

    f16x8 a[4], b1[4], b3[4];
    #pragma unroll
    for (int i = 0; i < 4; i++) {
      a[i]  = *(const f16x8*)(&Xs[p][(wm + i * 16 + lr) * 32 + q * 8]);
      b1[i] = *(const f16x8*)(&W1s[p][(wn + i * 16 + lr) * 32 + q * 8]);
      b3[i] = *(const f16x8*)(&W3s[p][(wn + i * 16 + lr) * 32 + q * 8]);
    }
    #pragma unroll
    for (int mi = 0; mi < 4; mi++)
      #pragma unroll
      for (int ni = 0; ni < 4; ni++) {
        au[mi][ni] = __builtin_amdgcn_mfma_f32_16x16x32_f16(a[mi], b1[ni], au[mi][ni], 0, 0, 0);
        av[mi][ni] = __builtin_amdgcn_mfma_f32_16x16x32_f16(a[mi], b3[ni], av[mi][ni], 0, 0, 0);
      }
    p ^= 1;
  }

  // epilogue: h = relu(u)^2 * v  (C/D layout: col = lane&15, row = quad*4 + reg)
  #pragma unroll
  for (int mi = 0; mi < 4; mi++) {
    #pragma unroll
    for (int r = 0; r < 4; r++) {
      int ml = wm + mi * 16 + q * 4 + r;
      if (m0 + ml < c) {
        long hrow = (long)sEnt[ml];
        _Float16* hp = hbuf + hrow * H_DIM + n0 + wn + lr;
        #pragma unroll
        for (int ni = 0; ni < 4; ni++) {
          float u = au[mi][ni][r];
          float rl = u > 0.f ? u : 0.f;
          float hv = rl * rl * av[mi][ni][r];
          hp[ni * 16] = (_Float16)hv;
        }
      }
    }
  }
}

// ---------------- stage 2: out += coef * (h @ W2^T), per expert ----------------
__global__ __launch_bounds__(256, 4) void ffn_stage2(
    const _Float16* __restrict__ hbuf, const _Float16* __restrict__ w2h,
    const int* __restrict__ cnt, const int* __restrict__ tokL,
    const float* __restrict__ coefL, float* __restrict__ out) {
  const int e  = blockIdx.z;
  const int n0 = blockIdx.y * 128;   // over D
  const int m0 = blockIdx.x * 128;
  const int c  = cnt[e];
  if (m0 >= c) return;

  __shared__ _Float16 Hs[2][128 * 32];
  __shared__ _Float16 W2s[2][128 * 32];
  __shared__ int sEnt[128];
  __shared__ float sCoef[128];

  const int t = threadIdx.x;
  if (t < 128) {
    int idx = m0 + t;
    if (idx >= c) idx = c - 1;
    sEnt[t]  = tokL[e * CAPL + idx];
    sCoef[t] = coefL[e * CAPL + idx];
  }
  __syncthreads();

  const int srow = t >> 2;
  const int c8   = (t & 3) * 8;
  const long hr0 = (long)sEnt[srow];
  const long hr1 = (long)sEnt[srow + 64];
  const _Float16* hg0 = hbuf + hr0 * H_DIM + c8;
  const _Float16* hg1 = hbuf + hr1 * H_DIM + c8;
  const _Float16* w2g0 = w2h + ((long)e * D_DIM + n0 + srow) * H_DIM + c8;
  const _Float16* w2g1 = w2g0 + (long)64 * H_DIM;
  const int l8 = t * 8;

  const int w = t >> 6, lane = t & 63;
  const int wm = (w & 1) * 64, wn = (w >> 1) * 64;
  const int q = lane >> 4, lr = lane & 15;

  f32x4 ac[4][4];
  const f32x4 zz = {0.f, 0.f, 0.f, 0.f};
  #pragma unroll
  for (int i = 0; i < 4; i++)
    #pragma unroll
    for (int j = 0; j < 4; j++) ac[i][j] = zz;

  gload16(hg0,  &Hs[0][l8]);
  gload16(hg1,  &Hs[0][2048 + l8]);
  gload16(w2g0, &W2s[0][l8]);
  gload16(w2g1, &W2s[0][2048 + l8]);

  int p = 0;
  for (int k0 = 0; k0 < H_DIM; k0 += 32) {
    __syncthreads();
    int kn = k0 + 32;
    if (kn < H_DIM) {
      int pn = p ^ 1;
      gload16(hg0 + kn,  &Hs[pn][l8]);
      gload16(hg1 + kn,  &Hs[pn][2048 + l8]);
      gload16(w2g0 + kn, &W2s[pn][l8]);
      gload16(w2g1 + kn, &W2s[pn][2048 + l8]);
    }

    f16x8 a[4], b[4];
    #pragma unroll
    for (int i = 0; i < 4; i++) {
      a[i] = *(const f16x8*)(&Hs[p][(wm + i * 16 + lr) * 32 + q * 8]);
      b[i] = *(const f16x8*)(&W2s[p][(wn + i * 16 + lr) * 32 + q * 8]);
    }
    #pragma unroll
    for (int mi = 0; mi < 4; mi++)
      #pragma unroll
      for (int ni = 0; ni < 4; ni++)
        ac[mi][ni] = __builtin_amdgcn_mfma_f32_16x16x32_f16(a[mi], b[ni], ac[mi][ni], 0, 0, 0);
    p ^= 1;
  }

  #pragma unroll
  for (int mi = 0; mi < 4; mi++) {
    #pragma unroll
    for (int r = 0; r < 4; r++) {
      int ml = wm + mi * 16 + q * 4 + r;
      if (m0 + ml < c) {
        int ent = sEnt[ml];
        int token = ent >> 1;
        float cf = sCoef[ml];
        float* op = out + (long)token * D_DIM + n0 + wn + lr;
        #pragma unroll
        for (int ni = 0; ni < 4; ni++)
          atomicAdd(op + ni * 16, cf * ac[mi][ni][r]);
      }
    }
  }
}

extern "C" void kernel_launch(void* const* d_in, const int* in_sizes, int n_in,
                              void* d_out, int out_size, void* d_ws, size_t ws_size,
                              hipStream_t stream) {
  (void)in_sizes; (void)n_in; (void)out_size; (void)ws_size;
  const float* x  = (const float*)d_in[0];
  const float* W1 = (const float*)d_in[1];
  const float* W2 = (const float*)d_in[2];   // dict order: x, W1, W2, W3, gate_w, gate_b
  const float* W3 = (const float*)d_in[3];
  const float* gw = (const float*)d_in[4];
  const float* gb = (const float*)d_in[5];
  float* out = (float*)d_out;

  // workspace layout (fp16 elements), ~185 MB total
  _Float16* xh  = (_Float16*)d_ws;
  _Float16* w1h = xh  + (size_t)N_TOK * D_DIM;
  _Float16* w3h = w1h + (size_t)N_EXP * H_DIM * D_DIM;
  _Float16* w2h = w3h + (size_t)N_EXP * H_DIM * D_DIM;
  _Float16* hb  = w2h + (size_t)N_EXP * H_DIM * D_DIM;
  int*   cnt   = (int*)(hb + (size_t)2 * N_TOK * H_DIM);
  int*   tokL  = cnt + 16;
  float* coefL = (float*)(tokL + N_EXP * CAPL);

  hipMemsetAsync(d_out, 0, (size_t)N_TOK * D_DIM * sizeof(float), stream);
  hipMemsetAsync(cnt, 0, 16 * sizeof(int), stream);

  int xn4 = N_TOK * D_DIM / 4;
  cvt_f32_f16<<<(xn4 + 255) / 256, 256, 0, stream>>>(x, xh, xn4);
  int wn4 = N_EXP * H_DIM * D_DIM / 4;
  cvt_f32_f16<<<(wn4 + 255) / 256, 256, 0, stream>>>(W1, w1h, wn4);
  cvt_f32_f16<<<(wn4 + 255) / 256, 256, 0, stream>>>(W3, w3h, wn4);
  cvt_f32_f16<<<(wn4 + 255) / 256, 256, 0, stream>>>(W2, w2h, wn4);

  gate_route<<<N_TOK / 4, 256, 0, stream>>>(x, gw, gb, cnt, tokL, coefL);

  // capacity 32*128 = 4096 rows/expert; cnt ~ 2048 +- 39 (1 sigma) -> >50 sigma margin
  ffn_stage1<<<dim3(32, H_DIM / 128, N_EXP), 256, 0, stream>>>(xh, w1h, w3h, cnt, tokL, hb);
  ffn_stage2<<<dim3(32, D_DIM / 128, N_EXP), 256, 0, stream>>>(hb, w2h, cnt, tokL, coefL, out);
}

// Round 3
// 779.436 us; speedup vs baseline: 1.5103x; 1.4705x over previous
//
#include <hip/hip_runtime.h>
#include <hip/hip_fp16.h>
#include <math.h>

#define N_TOK 8192
#define D_DIM 1024
#define H_DIM 2048
#define N_EXP 8
#define CAPL  8192
#define MT1   18      // m-tiles per expert (capacity 2304 rows; cnt ~ 2048 +- 39)

typedef _Float16 f16x8 __attribute__((ext_vector_type(8)));
typedef float    f32x4 __attribute__((ext_vector_type(4)));

__device__ __forceinline__ void gload16(const void* g, void* l) {
  __builtin_amdgcn_global_load_lds(
      (const __attribute__((address_space(1))) void*)g,
      (__attribute__((address_space(3))) void*)l, 16, 0, 0);
}

// ---------------- x: fp32 -> fp16, linear ----------------
__global__ __launch_bounds__(256) void cvt_f32_f16(const float* __restrict__ s,
                                                   _Float16* __restrict__ d, int n4) {
  int i = blockIdx.x * 256 + threadIdx.x;
  if (i >= n4) return;
  float4 v = ((const float4*)s)[i];
  _Float16 o0 = (_Float16)v.x, o1 = (_Float16)v.y, o2 = (_Float16)v.z, o3 = (_Float16)v.w;
  __attribute__((ext_vector_type(4))) _Float16 o = {o0, o1, o2, o3};
  ((__attribute__((ext_vector_type(4))) _Float16*)d)[i] = o;
}

// ---- weights: [E][R][K] fp32 -> tile-packed [E][R/128][K/32][128*32] fp16 ----
// packed element (r, c) of tile (e, rt, kc) sits at linear offset r*32+c — the
// exact LDS order the GEMM kernels stage, so staging loads are fully linear.
__global__ __launch_bounds__(256) void pack_w(const float* __restrict__ src,
                                              _Float16* __restrict__ dst,
                                              int R, int K) {
  const int e = blockIdx.z, rt = blockIdx.y, kc = blockIdx.x;
  const int t = threadIdx.x;
  const int r = t >> 1, c = (t & 1) * 16;
  const float* s = src + ((long)e * R + (long)rt * 128 + r) * K + kc * 32 + c;
  const float4 v0 = ((const float4*)s)[0];
  const float4 v1 = ((const float4*)s)[1];
  const float4 v2 = ((const float4*)s)[2];
  const float4 v3 = ((const float4*)s)[3];
  f16x8 o0, o1;
  o0[0]=(_Float16)v0.x; o0[1]=(_Float16)v0.y; o0[2]=(_Float16)v0.z; o0[3]=(_Float16)v0.w;
  o0[4]=(_Float16)v1.x; o0[5]=(_Float16)v1.y; o0[6]=(_Float16)v1.z; o0[7]=(_Float16)v1.w;
  o1[0]=(_Float16)v2.x; o1[1]=(_Float16)v2.y; o1[2]=(_Float16)v2.z; o1[3]=(_Float16)v2.w;
  o1[4]=(_Float16)v3.x; o1[5]=(_Float16)v3.y; o1[6]=(_Float16)v3.z; o1[7]=(_Float16)v3.w;
  _Float16* d = dst + (((long)e * (R >> 7) + rt) * (K >> 5) + kc) * 4096 + t * 16;
  ((f16x8*)d)[0] = o0;
  ((f16x8*)d)[1] = o1;
}

// ---------------- gating + routing (fp64 acc -> exact top-2) ----------------
__global__ __launch_bounds__(256) void gate_route(
    const float* __restrict__ x, const float* __restrict__ gw,
    const float* __restrict__ gb, int* __restrict__ cnt,
    int* __restrict__ tokL, float* __restrict__ coefL) {
  __shared__ float sgw[N_EXP * D_DIM];
  for (int i = threadIdx.x; i < N_EXP * D_DIM; i += 256) sgw[i] = gw[i];
  __syncthreads();
  const int w = threadIdx.x >> 6, lane = threadIdx.x & 63;
  const int n = blockIdx.x * 4 + w;
  const float* xp = x + (long)n * D_DIM;
  double acc[N_EXP];
  #pragma unroll
  for (int e = 0; e < N_EXP; e++) acc[e] = 0.0;
  for (int i = 0; i < D_DIM / 64; i++) {
    int d = lane + i * 64;
    double xv = (double)xp[d];
    #pragma unroll
    for (int e = 0; e < N_EXP; e++) acc[e] += xv * (double)sgw[e * D_DIM + d];
  }
  #pragma unroll
  for (int e = 0; e < N_EXP; e++)
    for (int off = 32; off >= 1; off >>= 1)
      acc[e] += __shfl_down(acc[e], off);
  if (lane == 0) {
    double lg[N_EXP];
    #pragma unroll
    for (int e = 0; e < N_EXP; e++) lg[e] = acc[e] + (double)gb[e];
    int i1 = 0;
    for (int e = 1; e < N_EXP; e++) if (lg[e] > lg[i1]) i1 = e;
    int i2 = (i1 == 0) ? 1 : 0;
    for (int e = 0; e < N_EXP; e++) { if (e == i1) continue; if (lg[e] > lg[i2]) i2 = e; }
    double p1 = 1.0 / (1.0 + exp(lg[i2] - lg[i1]));
    double p2 = 1.0 - p1;
    int pos1 = atomicAdd(&cnt[i1], 1);
    tokL[i1 * CAPL + pos1] = n * 2;
    coefL[i1 * CAPL + pos1] = (float)p1;
    int pos2 = atomicAdd(&cnt[i2], 1);
    tokL[i2 * CAPL + pos2] = n * 2 + 1;
    coefL[i2 * CAPL + pos2] = (float)p2;
  }
}

// ---------------- stage 1: h = relu(x@W1^T)^2 * (x@W3^T) ----------------
// 384 threads: waves 0-3 = MFMA consumers, waves 4-5 = loaders (producer).
// Triple-buffered LDS, depth-2 pipeline; producer syncs with raw
// s_waitcnt vmcnt(12)+s_barrier so prefetch loads stay in flight across
// barriers; consumers' __syncthreads drains a vmcnt that is already 0.
__global__ __launch_bounds__(384, 2) void ffn_stage1(
    const _Float16* __restrict__ xh, const _Float16* __restrict__ w1p,
    const _Float16* __restrict__ w3p, const int* __restrict__ cnt,
    const int* __restrict__ tokL, _Float16* __restrict__ hbuf) {
  const int e = blockIdx.z, nt = blockIdx.y, mt = blockIdx.x;
  const int m0 = mt * 128;
  const int c = cnt[e];
  if (m0 >= c) return;

  __shared__ _Float16 Xs[3][4096];
  __shared__ _Float16 W1s[3][4096];
  __shared__ _Float16 W3s[3][4096];
  __shared__ int sEnt[128];

  const int t = threadIdx.x;
  if (t < 128) {
    int idx = m0 + t; if (idx >= c) idx = c - 1;   // clamp; stores guarded later
    sEnt[t] = tokL[e * CAPL + idx];
  }
  __syncthreads();

  if (t >= 256) {
    // -------- producer: 128 threads, 12 x 16B loads per K-iter --------
    const int pt = t - 256;
    const int cx = (pt & 3) * 8;
    const _Float16* xsrc[4];
    #pragma unroll
    for (int j = 0; j < 4; j++)
      xsrc[j] = xh + (long)(sEnt[(pt >> 2) + 32 * j] >> 1) * D_DIM + cx;
    const _Float16* w1t = w1p + (long)(e * 16 + nt) * 32 * 4096 + pt * 8;
    const _Float16* w3t = w3p + (long)(e * 16 + nt) * 32 * 4096 + pt * 8;
    const int l0 = pt * 8;

    auto stage = [&](int b, int kc) {
      #pragma unroll
      for (int j = 0; j < 4; j++)
        gload16(xsrc[j] + kc * 32, &Xs[b][l0 + j * 1024]);
      #pragma unroll
      for (int j = 0; j < 4; j++)
        gload16(w1t + (long)kc * 4096 + j * 1024, &W1s[b][l0 + j * 1024]);
      #pragma unroll
      for (int j = 0; j < 4; j++)
        gload16(w3t + (long)kc * 4096 + j * 1024, &W3s[b][l0 + j * 1024]);
    };

    stage(0, 0); stage(1, 1);
    __asm__ volatile("s_waitcnt vmcnt(12)\n\ts_barrier");   // B0: buf0 ready
    for (int kc = 0; kc < 32; ++kc) {
      if (kc + 2 < 32) {
        stage((kc + 2) % 3, kc + 2);
        __asm__ volatile("s_waitcnt vmcnt(12)\n\ts_barrier");  // buf kc+1 ready
      } else {
        __asm__ volatile("s_waitcnt vmcnt(0)\n\ts_barrier");
      }
    }
    return;
  }

  // -------- consumers: 4 waves, 128x128 tile, dual GEMM --------
  const int w = t >> 6, lane = t & 63;
  const int wm = (w & 1) * 64, wn = (w >> 1) * 64;
  const int q = lane >> 4, lr = lane & 15;

  f32x4 au[4][4], av[4][4];
  const f32x4 zz = {0.f, 0.f, 0.f, 0.f};
  #pragma unroll
  for (int i = 0; i < 4; i++)
    #pragma unroll
    for (int j = 0; j < 4; j++) { au[i][j] = zz; av[i][j] = zz; }

  __syncthreads();                     // B0
  for (int kc = 0; kc < 32; ++kc) {
    const int p = kc % 3;
    f16x8 a[4], b1[4], b3[4];
    #pragma unroll
    for (int i = 0; i < 4; i++) {
      a[i]  = *(const f16x8*)(&Xs[p][(wm + i * 16 + lr) * 32 + q * 8]);
      b1[i] = *(const f16x8*)(&W1s[p][(wn + i * 16 + lr) * 32 + q * 8]);
      b3[i] = *(const f16x8*)(&W3s[p][(wn + i * 16 + lr) * 32 + q * 8]);
    }
    #pragma unroll
    for (int mi = 0; mi < 4; mi++)
      #pragma unroll
      for (int ni = 0; ni < 4; ni++) {
        au[mi][ni] = __builtin_amdgcn_mfma_f32_16x16x32_f16(a[mi], b1[ni], au[mi][ni], 0, 0, 0);
        av[mi][ni] = __builtin_amdgcn_mfma_f32_16x16x32_f16(a[mi], b3[ni], av[mi][ni], 0, 0, 0);
      }
    __syncthreads();                   // B_{kc+1}
  }

  // epilogue: packed h tile (e, mt), kchunks nt*4 .. nt*4+3, row = list position
  const long tb = ((long)(e * MT1 + mt) * 64 + nt * 4) * 4096;
  #pragma unroll
  for (int mi = 0; mi < 4; mi++) {
    #pragma unroll
    for (int r = 0; r < 4; r++) {
      int ml = wm + mi * 16 + q * 4 + r;
      if (m0 + ml < c) {
        #pragma unroll
        for (int ni = 0; ni < 4; ni++) {
          int colb = wn + ni * 16;
          float u = au[mi][ni][r];
          float rl = u > 0.f ? u : 0.f;
          float hv = rl * rl * av[mi][ni][r];
          hbuf[tb + (long)(colb >> 5) * 4096 + ml * 32 + (colb & 31) + lr] = (_Float16)hv;
        }
      }
    }
  }
}

// ---------------- stage 2: out += coef * (h @ W2^T), split-K x2 ----------------
__global__ __launch_bounds__(384, 3) void ffn_stage2(
    const _Float16* __restrict__ hbuf, const _Float16* __restrict__ w2p,
    const int* __restrict__ cnt, const int* __restrict__ tokL,
    const float* __restrict__ coefL, float* __restrict__ out) {
  const int e = blockIdx.z >> 1, ks = blockIdx.z & 1;
  const int dt = blockIdx.y, mt = blockIdx.x;
  const int m0 = mt * 128;
  const int c = cnt[e];
  if (m0 >= c) return;

  __shared__ _Float16 Hs[3][4096];
  __shared__ _Float16 W2s[3][4096];
  __shared__ int sEnt[128];
  __shared__ float sCoef[128];

  const int t = threadIdx.x;
  if (t < 128) {
    int idx = m0 + t; if (idx >= c) idx = c - 1;
    sEnt[t]  = tokL[e * CAPL + idx];
    sCoef[t] = coefL[e * CAPL + idx];
  }
  __syncthreads();

  if (t >= 256) {
    // -------- producer: 8 x 16B loads per K-iter, all linear --------
    const int pt = t - 256;
    const _Float16* hA  = hbuf + ((long)(e * MT1 + mt) * 64 + ks * 32) * 4096 + pt * 8;
    const _Float16* w2t = w2p  + ((long)(e * 8 + dt) * 64 + ks * 32) * 4096 + pt * 8;
    const int l0 = pt * 8;

    auto stage = [&](int b, int kc) {
      #pragma unroll
      for (int j = 0; j < 4; j++)
        gload16(hA + (long)kc * 4096 + j * 1024, &Hs[b][l0 + j * 1024]);
      #pragma unroll
      for (int j = 0; j < 4; j++)
        gload16(w2t + (long)kc * 4096 + j * 1024, &W2s[b][l0 + j * 1024]);
    };

    stage(0, 0); stage(1, 1);
    __asm__ volatile("s_waitcnt vmcnt(8)\n\ts_barrier");
    for (int kc = 0; kc < 32; ++kc) {
      if (kc + 2 < 32) {
        stage((kc + 2) % 3, kc + 2);
        __asm__ volatile("s_waitcnt vmcnt(8)\n\ts_barrier");
      } else {
        __asm__ volatile("s_waitcnt vmcnt(0)\n\ts_barrier");
      }
    }
    return;
  }

  const int w = t >> 6, lane = t & 63;
  const int wm = (w & 1) * 64, wn = (w >> 1) * 64;
  const int q = lane >> 4, lr = lane & 15;

  f32x4 ac[4][4];
  const f32x4 zz = {0.f, 0.f, 0.f, 0.f};
  #pragma unroll
  for (int i = 0; i < 4; i++)
    #pragma unroll
    for (int j = 0; j < 4; j++) ac[i][j] = zz;

  __syncthreads();
  for (int kc = 0; kc < 32; ++kc) {
    const int p = kc % 3;
    f16x8 a[4], b[4];
    #pragma unroll
    for (int i = 0; i < 4; i++) {
      a[i] = *(const f16x8*)(&Hs[p][(wm + i * 16 + lr) * 32 + q * 8]);
      b[i] = *(const f16x8*)(&W2s[p][(wn + i * 16 + lr) * 32 + q * 8]);
    }
    #pragma unroll
    for (int mi = 0; mi < 4; mi++)
      #pragma unroll
      for (int ni = 0; ni < 4; ni++)
        ac[mi][ni] = __builtin_amdgcn_mfma_f32_16x16x32_f16(a[mi], b[ni], ac[mi][ni], 0, 0, 0);
    __syncthreads();
  }

  const int n0 = dt * 128;
  #pragma unroll
  for (int mi = 0; mi < 4; mi++) {
    #pragma unroll
    for (int r = 0; r < 4; r++) {
      int ml = wm + mi * 16 + q * 4 + r;
      if (m0 + ml < c) {
        int token = sEnt[ml] >> 1;
        float cf = sCoef[ml];
        float* op = out + (long)token * D_DIM + n0 + wn + lr;
        #pragma unroll
        for (int ni = 0; ni < 4; ni++)
          atomicAdd(op + ni * 16, cf * ac[mi][ni][r]);
      }
    }
  }
}

extern "C" void kernel_launch(void* const* d_in, const int* in_sizes, int n_in,
                              void* d_out, int out_size, void* d_ws, size_t ws_size,
                              hipStream_t stream) {
  (void)in_sizes; (void)n_in; (void)out_size; (void)ws_size;
  const float* x  = (const float*)d_in[0];
  const float* W1 = (const float*)d_in[1];
  const float* W2 = (const float*)d_in[2];   // dict order: x, W1, W2, W3, gate_w, gate_b
  const float* W3 = (const float*)d_in[3];
  const float* gw = (const float*)d_in[4];
  const float* gb = (const float*)d_in[5];
  float* out = (float*)d_out;

  // workspace layout (fp16 elements), ~194 MB total
  _Float16* xh  = (_Float16*)d_ws;
  _Float16* w1p = xh  + (size_t)N_TOK * D_DIM;
  _Float16* w3p = w1p + (size_t)N_EXP * H_DIM * D_DIM;
  _Float16* w2p = w3p + (size_t)N_EXP * H_DIM * D_DIM;
  _Float16* hb  = w2p + (size_t)N_EXP * H_DIM * D_DIM;           // packed: E*MT1*64*4096
  int*   cnt   = (int*)(hb + (size_t)N_EXP * MT1 * 64 * 4096);
  int*   tokL  = cnt + 16;
  float* coefL = (float*)(tokL + N_EXP * CAPL);

  hipMemsetAsync(d_out, 0, (size_t)N_TOK * D_DIM * sizeof(float), stream);
  hipMemsetAsync(cnt, 0, 16 * sizeof(int), stream);

  int xn4 = N_TOK * D_DIM / 4;
  cvt_f32_f16<<<(xn4 + 255) / 256, 256, 0, stream>>>(x, xh, xn4);
  pack_w<<<dim3(D_DIM / 32, H_DIM / 128, N_EXP), 256, 0, stream>>>(W1, w1p, H_DIM, D_DIM);
  pack_w<<<dim3(D_DIM / 32, H_DIM / 128, N_EXP), 256, 0, stream>>>(W3, w3p, H_DIM, D_DIM);
  pack_w<<<dim3(H_DIM / 32, D_DIM / 128, N_EXP), 256, 0, stream>>>(W2, w2p, D_DIM, H_DIM);

  gate_route<<<N_TOK / 4, 256, 0, stream>>>(x, gw, gb, cnt, tokL, coefL);

  ffn_stage1<<<dim3(MT1, H_DIM / 128, N_EXP), 384, 0, stream>>>(xh, w1p, w3p, cnt, tokL, hb);
  ffn_stage2<<<dim3(MT1, D_DIM / 128, N_EXP * 2), 384, 0, stream>>>(hb, w2p, cnt, tokL, coefL, out);
}